// Round 7
// baseline (154.471 us; speedup 1.0000x reference)
//
#include <hip/hip_runtime.h>

// LR_PINN_phase2_midout: fused 4-stage tiny MLP, N=262144, H=256, R=32.
// R7 = R6 + (a) 2*log2e folded into all tanh-feeding weights at staging
//          (b) 1-deep software prefetch of every LDS fragment
//          (c) source-interleaved dual streams.
// R6 post-mortem: VGPR stayed 52 -> compiler serialized the two streams to
// save registers; dependency stalls (LDS ~120cyc, trans chain) kept VALUBusy
// at 72%. Prefetch moves every load one body ahead; scale-folding deletes
// one VALU op per tanh (256k/tile); interleaved streams give the scheduler
// two independent chains per body. Live set ~60 regs — under the 64 budget.
//
// MFMA chain (mfma_f32_16x16x16f16): C/D layout (col=lane&15=point,
// row=4q+reg) == next MFMA's B-frag layout (k=4q+jj) -> phase0 ->
// (GEMM1 -> GEMM2 -> tanh)^3 -> dot is layout-closed in registers.
// Fragment-ordered LDS: every hot read is base + lane*8, conflict-free.

typedef _Float16 half4_t __attribute__((ext_vector_type(4)));
typedef float    float4_t __attribute__((ext_vector_type(4)));

#define TANH_SCALE 2.885390081777927f  // 2*log2(e); exp2(S*x) == exp(2x)

namespace {

struct Smem {
  // entry index e = ((k*16+t)*2+sel)*64+lane ; one half4 (8 B) per lane.
  half4_t ctf[3 * 16 * 2 * 64];  // 48 KB: Ct[sel*16+m][16t+4q+jj] * alpha   (A-frags, GEMM1)
  half4_t rwf[3 * 16 * 2 * 64];  // 48 KB: S * R[16t+m][sel*16+4q+jj]        (A-frags, GEMM2)
  float w0[256], w1[256], bb[256], ew[256];  // 4 KB (w0,w1,bb pre-scaled by S)
};

// input pre-scaled by S: tanh(x) = 1 - 2/(1 + exp2(S*x)); exact sat at +-inf.
__device__ __forceinline__ float tanh_pre(float y) {
  const float e = __builtin_amdgcn_exp2f(y);
  return fmaf(-2.0f, __builtin_amdgcn_rcpf(e + 1.0f), 1.0f);
}

__device__ __forceinline__ half4_t tanh4_pre(float4_t v) {
  half4_t h;
  h.x = (_Float16)tanh_pre(v.x);
  h.y = (_Float16)tanh_pre(v.y);
  h.z = (_Float16)tanh_pre(v.z);
  h.w = (_Float16)tanh_pre(v.w);
  return h;
}

__device__ __forceinline__ half4_t pack16(float4_t v) {
  half4_t h;
  h.x = (_Float16)v.x; h.y = (_Float16)v.y; h.z = (_Float16)v.z; h.w = (_Float16)v.w;
  return h;
}

__global__ __launch_bounds__(1024)
__attribute__((amdgpu_waves_per_eu(4, 4)))
void pinn_fused(
    const float* __restrict__ xg, const float* __restrict__ tg,
    const float* __restrict__ sw, const float* __restrict__ sb,
    const float* __restrict__ ewp, const float* __restrict__ ebp,
    const float* __restrict__ c0, const float* __restrict__ c1,
    const float* __restrict__ c2, const float* __restrict__ r0,
    const float* __restrict__ r1, const float* __restrict__ r2,
    const float* __restrict__ a0, const float* __restrict__ a1,
    const float* __restrict__ a2, float* __restrict__ out, int n)
{
  __shared__ Smem sm;
  const int tid = threadIdx.x;

  // ---- stage weights into fragment-ordered fp16 LDS (once per block) ----
  for (int e = tid; e < 3 * 16 * 2 * 64; e += 1024) {
    const int lane_ = e & 63;
    const int sel   = (e >> 6) & 1;
    const int t_    = (e >> 7) & 15;
    const int k_    = e >> 11;
    const int m_ = lane_ & 15, q_ = lane_ >> 4;
    const float* ck = (k_ == 0) ? c0 : (k_ == 1) ? c1 : c2;
    const float* rk = (k_ == 0) ? r0 : (k_ == 1) ? r1 : r2;
    const float* ak = (k_ == 0) ? a0 : (k_ == 1) ? a1 : a2;
    {  // Ct frag: A-row r = sel*16+m, cols j = 16t+4q+jj ; fold diag(alpha)
      const int r = sel * 16 + m_;
      const float av = ak[r];
      const int j0 = 16 * t_ + 4 * q_;
      half4_t v;
      v.x = (_Float16)(ck[(j0 + 0) * 32 + r] * av);
      v.y = (_Float16)(ck[(j0 + 1) * 32 + r] * av);
      v.z = (_Float16)(ck[(j0 + 2) * 32 + r] * av);
      v.w = (_Float16)(ck[(j0 + 3) * 32 + r] * av);
      sm.ctf[e] = v;
    }
    {  // R frag: A-row j = 16t+m, cols r = sel*16+4q+jj ; fold tanh scale S
      const int j = 16 * t_ + m_;
      const int rr = sel * 16 + 4 * q_;
      half4_t v;
      v.x = (_Float16)(rk[j * 32 + rr + 0] * TANH_SCALE);
      v.y = (_Float16)(rk[j * 32 + rr + 1] * TANH_SCALE);
      v.z = (_Float16)(rk[j * 32 + rr + 2] * TANH_SCALE);
      v.w = (_Float16)(rk[j * 32 + rr + 3] * TANH_SCALE);
      sm.rwf[e] = v;
    }
  }
  if (tid < 256) {
    sm.w0[tid] = sw[2 * tid] * TANH_SCALE;      // fold tanh scale S
    sm.w1[tid] = sw[2 * tid + 1] * TANH_SCALE;
    sm.bb[tid] = sb[tid] * TANH_SCALE;
    sm.ew[tid] = ewp[tid];
  }
  __syncthreads();  // the only barrier

  const int wave = tid >> 6;
  const int lane = tid & 63;
  const int m = lane & 15;   // point index (MFMA col / A-row / B-col)
  const int q = lane >> 4;   // quad
  const int wo = 4 * q;      // j = 16t + 4q + jj
  const float ebv = ebp[0];
  const int tiles = n >> 4;

#pragma unroll 1
  for (int g = blockIdx.x * 32 + wave * 2; g < tiles; g += 8192) {
    const int n0 = g * 16;
    const int n1 = n0 + 16;
    const float xm0 = xg[n0 + m], tm0 = tg[n0 + m];
    const float xm1 = xg[n1 + m], tm1 = tg[n1 + m];

    // ---- phase0 fused with GEMM1(k=0); prefetched, dual interleaved streams ----
    float4_t a00 = {0.f, 0.f, 0.f, 0.f}, a01 = {0.f, 0.f, 0.f, 0.f};
    float4_t a10 = {0.f, 0.f, 0.f, 0.f}, a11 = {0.f, 0.f, 0.f, 0.f};
    {
      const half4_t* cp = &sm.ctf[lane];
      float4_t w0v = *(const float4_t*)&sm.w0[wo];
      float4_t w1v = *(const float4_t*)&sm.w1[wo];
      float4_t bv  = *(const float4_t*)&sm.bb[wo];
      half4_t cA = cp[0], cB = cp[64];
#pragma unroll 1
      for (int t = 0; t < 16; ++t) {
        // prefetch body t+1 (t=15 overruns into adjacent Smem members: in-bounds, unused)
        const float4_t w0n = *(const float4_t*)&sm.w0[(t + 1) * 16 + wo];
        const float4_t w1n = *(const float4_t*)&sm.w1[(t + 1) * 16 + wo];
        const float4_t bn  = *(const float4_t*)&sm.bb[(t + 1) * 16 + wo];
        const half4_t cAn = cp[128], cBn = cp[192];
        float4_t z0, z1;
        z0.x = fmaf(xm0, w0v.x, fmaf(tm0, w1v.x, bv.x));
        z1.x = fmaf(xm1, w0v.x, fmaf(tm1, w1v.x, bv.x));
        z0.y = fmaf(xm0, w0v.y, fmaf(tm0, w1v.y, bv.y));
        z1.y = fmaf(xm1, w0v.y, fmaf(tm1, w1v.y, bv.y));
        z0.z = fmaf(xm0, w0v.z, fmaf(tm0, w1v.z, bv.z));
        z1.z = fmaf(xm1, w0v.z, fmaf(tm1, w1v.z, bv.z));
        z0.w = fmaf(xm0, w0v.w, fmaf(tm0, w1v.w, bv.w));
        z1.w = fmaf(xm1, w0v.w, fmaf(tm1, w1v.w, bv.w));
        const half4_t h0 = tanh4_pre(z0);
        const half4_t h1 = tanh4_pre(z1);
        a00 = __builtin_amdgcn_mfma_f32_16x16x16f16(cA, h0, a00, 0, 0, 0);
        a10 = __builtin_amdgcn_mfma_f32_16x16x16f16(cA, h1, a10, 0, 0, 0);
        a01 = __builtin_amdgcn_mfma_f32_16x16x16f16(cB, h0, a01, 0, 0, 0);
        a11 = __builtin_amdgcn_mfma_f32_16x16x16f16(cB, h1, a11, 0, 0, 0);
        w0v = w0n; w1v = w1n; bv = bn; cA = cAn; cB = cBn;
        cp += 128;
      }
    }

    float ssum0 = 0.0f, ssum1 = 0.0f;
#pragma unroll 1
    for (int k = 0; k < 3; ++k) {
      // acc (= P^T, r = 4q+reg) is already the next B-frag: just pack fp16.
      const half4_t pA0 = pack16(a00), pB0 = pack16(a01);
      const half4_t pA1 = pack16(a10), pB1 = pack16(a11);

      if (k < 2) {
        // GEMM2(k) fused with GEMM1(k+1); prefetched, dual interleaved streams.
        float4_t n00 = {0.f, 0.f, 0.f, 0.f}, n01 = {0.f, 0.f, 0.f, 0.f};
        float4_t n10 = {0.f, 0.f, 0.f, 0.f}, n11 = {0.f, 0.f, 0.f, 0.f};
        const half4_t* rp = &sm.rwf[k * 2048 + lane];
        const half4_t* cp = &sm.ctf[(k + 1) * 2048 + lane];
        half4_t rA = rp[0], rB = rp[64];
        half4_t cA = cp[0], cB = cp[64];
#pragma unroll 1
        for (int t = 0; t < 16; ++t) {
          // prefetch body t+1 (t=15 overruns into adjacent Smem members: in-bounds, unused)
          const half4_t rAn = rp[128], rBn = rp[192];
          const half4_t cAn = cp[128], cBn = cp[192];
          float4_t hc0 = {0.f, 0.f, 0.f, 0.f};
          float4_t hc1 = {0.f, 0.f, 0.f, 0.f};
          hc0 = __builtin_amdgcn_mfma_f32_16x16x16f16(rA, pA0, hc0, 0, 0, 0);
          hc1 = __builtin_amdgcn_mfma_f32_16x16x16f16(rA, pA1, hc1, 0, 0, 0);
          hc0 = __builtin_amdgcn_mfma_f32_16x16x16f16(rB, pB0, hc0, 0, 0, 0);
          hc1 = __builtin_amdgcn_mfma_f32_16x16x16f16(rB, pB1, hc1, 0, 0, 0);
          const half4_t h0 = tanh4_pre(hc0);  // inputs pre-scaled via rwf
          const half4_t h1 = tanh4_pre(hc1);
          n00 = __builtin_amdgcn_mfma_f32_16x16x16f16(cA, h0, n00, 0, 0, 0);
          n10 = __builtin_amdgcn_mfma_f32_16x16x16f16(cA, h1, n10, 0, 0, 0);
          n01 = __builtin_amdgcn_mfma_f32_16x16x16f16(cB, h0, n01, 0, 0, 0);
          n11 = __builtin_amdgcn_mfma_f32_16x16x16f16(cB, h1, n11, 0, 0, 0);
          rA = rAn; rB = rBn; cA = cAn; cB = cBn;
          rp += 128;
          cp += 128;
        }
        a00 = n00; a01 = n01; a10 = n10; a11 = n11;
      } else {
        // last block: GEMM2(2) fused with the end_w dot (fp32 epilogue)
        const half4_t* rp = &sm.rwf[2 * 2048 + lane];
        half4_t rA = rp[0], rB = rp[64];
        float4_t ev = *(const float4_t*)&sm.ew[wo];
#pragma unroll 1
        for (int t = 0; t < 16; ++t) {
          const half4_t rAn = rp[128], rBn = rp[192];  // t=15 overrun: in-bounds of Smem
          const float4_t evn = *(const float4_t*)&sm.ew[((t + 1) & 15) * 16 + wo];
          float4_t hc0 = {0.f, 0.f, 0.f, 0.f};
          float4_t hc1 = {0.f, 0.f, 0.f, 0.f};
          hc0 = __builtin_amdgcn_mfma_f32_16x16x16f16(rA, pA0, hc0, 0, 0, 0);
          hc1 = __builtin_amdgcn_mfma_f32_16x16x16f16(rA, pA1, hc1, 0, 0, 0);
          hc0 = __builtin_amdgcn_mfma_f32_16x16x16f16(rB, pB0, hc0, 0, 0, 0);
          hc1 = __builtin_amdgcn_mfma_f32_16x16x16f16(rB, pB1, hc1, 0, 0, 0);
          ssum0 += tanh_pre(hc0.x) * ev.x + tanh_pre(hc0.y) * ev.y
                 + tanh_pre(hc0.z) * ev.z + tanh_pre(hc0.w) * ev.w;
          ssum1 += tanh_pre(hc1.x) * ev.x + tanh_pre(hc1.y) * ev.y
                 + tanh_pre(hc1.z) * ev.z + tanh_pre(hc1.w) * ev.w;
          rA = rAn; rB = rBn; ev = evn;
          rp += 128;
        }
      }
    }
    // reduce each stream's partial dot over the 4 quads
    ssum0 += __shfl_xor(ssum0, 16);
    ssum0 += __shfl_xor(ssum0, 32);
    ssum1 += __shfl_xor(ssum1, 16);
    ssum1 += __shfl_xor(ssum1, 32);
    if (lane < 16) {
      out[n0 + m] = ssum0 + ebv;
      out[n1 + m] = ssum1 + ebv;
    }
  }
}

}  // namespace

extern "C" void kernel_launch(void* const* d_in, const int* in_sizes, int n_in,
                              void* d_out, int out_size, void* d_ws, size_t ws_size,
                              hipStream_t stream) {
  const float* xg  = (const float*)d_in[0];
  const float* tg  = (const float*)d_in[1];
  const float* sw  = (const float*)d_in[2];
  const float* sb  = (const float*)d_in[3];
  const float* ewp = (const float*)d_in[4];
  const float* ebp = (const float*)d_in[5];
  const float* c0  = (const float*)d_in[6];
  const float* c1  = (const float*)d_in[7];
  const float* c2  = (const float*)d_in[8];
  const float* r0  = (const float*)d_in[9];
  const float* r1  = (const float*)d_in[10];
  const float* r2  = (const float*)d_in[11];
  const float* a0  = (const float*)d_in[12];
  const float* a1  = (const float*)d_in[13];
  const float* a2  = (const float*)d_in[14];
  float* outp = (float*)d_out;

  const int n = in_sizes[0];  // 262144

  pinn_fused<<<256, 1024, 0, stream>>>(xg, tg, sw, sb, ewp, ebp,
                                       c0, c1, c2, r0, r1, r2, a0, a1, a2,
                                       outp, n);
}